// Round 7
// baseline (328.174 us; speedup 1.0000x reference)
//
#include <hip/hip_runtime.h>
#include <hip/hip_fp16.h>

#define LRELU(v) ((v) > 0.f ? (v) : 0.2f * (v))

typedef _Float16 f16x8 __attribute__((ext_vector_type(8)));
typedef float f32x4 __attribute__((ext_vector_type(4)));

__device__ __forceinline__ f16x8 f16x8_zero() {
    f16x8 v;
#pragma unroll
    for (int j = 0; j < 8; ++j) v[j] = (_Float16)0.f;
    return v;
}

// ---------------- CSR construction ----------------
__global__ __launch_bounds__(256) void hist_kernel(const int* __restrict__ dst,
                                                   int* __restrict__ cnt, int E) {
    int e = blockIdx.x * 256 + threadIdx.x;
    if (e < E) atomicAdd(&cnt[dst[e]], 1);
}

__global__ __launch_bounds__(256) void scan_blk(const int* __restrict__ cnt,
                                                int* __restrict__ offv,
                                                int* __restrict__ bsum, int N) {
    __shared__ int sh[256];
    const int t = threadIdx.x;
    const int base = blockIdx.x * 1024 + t * 4;
    int v0 = (base + 0 < N) ? cnt[base + 0] : 0;
    int v1 = (base + 1 < N) ? cnt[base + 1] : 0;
    int v2 = (base + 2 < N) ? cnt[base + 2] : 0;
    int v3 = (base + 3 < N) ? cnt[base + 3] : 0;
    const int T = v0 + v1 + v2 + v3;
    sh[t] = T;
    __syncthreads();
    for (int o = 1; o < 256; o <<= 1) {
        int x = (t >= o) ? sh[t - o] : 0;
        __syncthreads();
        sh[t] += x;
        __syncthreads();
    }
    const int excl = sh[t] - T;
    if (t == 255) bsum[blockIdx.x] = sh[255];
    if (base + 0 < N) offv[base + 0] = excl;
    if (base + 1 < N) offv[base + 1] = excl + v0;
    if (base + 2 < N) offv[base + 2] = excl + v0 + v1;
    if (base + 3 < N) offv[base + 3] = excl + v0 + v1 + v2;
}

__global__ __launch_bounds__(64) void scan_top(int* __restrict__ bsum,
                                               int* __restrict__ offv,
                                               int NB, int N) {
    const int t = threadIdx.x;
    const int v = (t < NB) ? bsum[t] : 0;
    int incl = v;
#pragma unroll
    for (int o = 1; o < 64; o <<= 1) {
        int x = __shfl_up(incl, o);
        if (t >= o) incl += x;
    }
    if (t < NB) bsum[t] = incl - v;
    if (t == NB - 1) offv[N] = incl;
}

__global__ __launch_bounds__(256) void scan_add(int* __restrict__ offv,
                                                const int* __restrict__ bsum, int N) {
    const int base = blockIdx.x * 1024 + threadIdx.x * 4;
    const int add = bsum[blockIdx.x];
#pragma unroll
    for (int i = 0; i < 4; ++i)
        if (base + i < N) offv[base + i] += add;
}

__global__ __launch_bounds__(256) void fill_kernel(const int* __restrict__ dst,
                                                   const int* __restrict__ srcv,
                                                   const int* __restrict__ offv,
                                                   int* __restrict__ cur,
                                                   int* __restrict__ csrsrc, int E) {
    int e = blockIdx.x * 256 + threadIdx.x;
    if (e < E) {
        int d = dst[e];
        int p = atomicAdd(&cur[d], 1);
        csrsrc[offv[d] + p] = srcv[e];
    }
}

// ---------------- weight prep: transpose f32 [K][Nn] -> f16 [Nn][K] ----------------
__global__ __launch_bounds__(256) void prep_w16(const float* __restrict__ W,
                                                _Float16* __restrict__ wt,
                                                int K, int Nn) {
    int idx = blockIdx.x * 256 + threadIdx.x;
    if (idx < K * Nn) {
        int k = idx / Nn, nn2 = idx - k * Nn;
        wt[(size_t)nn2 * K + k] = (_Float16)W[idx];
    }
}

// ---------------- f32 -> f16 convert (x input) ----------------
__global__ __launch_bounds__(256) void cvt_f16(const float* __restrict__ in,
                                               _Float16* __restrict__ out, int n4) {
    int i = blockIdx.x * 256 + threadIdx.x;
    if (i < n4) {
        float4 v = *(const float4*)(in + (size_t)i * 4);
        _Float16 o[4] = {(_Float16)v.x, (_Float16)v.y, (_Float16)v.z, (_Float16)v.w};
        *(float2*)(out + (size_t)i * 4) = *(float2*)o;
    }
}

// ---------------- f16 MFMA GEMM, LDS-staged A, fused alpha + f16 h out ----------
template <int WM, int WN, int K, int H>
__global__ __launch_bounds__(WM * WN * 64) void gemm_f16_fused(
    const _Float16* __restrict__ A, const _Float16* __restrict__ Wt,
    const float* __restrict__ a_s, const float* __restrict__ a_d,
    _Float16* __restrict__ hout, float* __restrict__ als,
    float* __restrict__ ald, int M, int Nn) {
    constexpr int BM = WM * 64;
    constexpr int T = WM * WN * 64;
    constexpr int CHUNKS = BM * 16;
    __shared__ f16x8 Atile[BM * 16];
    const int t = threadIdx.x;
    const int lane = t & 63;
    const int wv = t >> 6;
    const int wm = wv / WN, wn = wv % WN;
    const int m0 = blockIdx.x * BM;
    const int n0 = blockIdx.y * (WN * 64);
    const int l15 = lane & 15, lg = lane >> 4;

    f32x4 acc[4][4];
    const f32x4 zz = {0.f, 0.f, 0.f, 0.f};
#pragma unroll
    for (int mi = 0; mi < 4; ++mi)
#pragma unroll
        for (int ni = 0; ni < 4; ++ni) acc[mi][ni] = zz;

    for (int kc = 0; kc < K; kc += 128) {
        __syncthreads();
#pragma unroll
        for (int i = 0; i < CHUNKS / T; ++i) {
            const int c = i * T + t;
            const int row = c >> 4, cc = c & 15;
            const int gr = m0 + row;
            f16x8 v = (gr < M) ? *(const f16x8*)(A + (size_t)gr * K + kc + cc * 8)
                               : f16x8_zero();
            Atile[(row * 16 + cc) ^ (row & 7)] = v;
        }
        __syncthreads();
#pragma unroll
        for (int ks = 0; ks < 4; ++ks) {
            f16x8 af[4], bf[4];
#pragma unroll
            for (int mi = 0; mi < 4; ++mi) {
                const int row = wm * 64 + mi * 16 + l15;
                af[mi] = Atile[(row * 16 + ks * 4 + lg) ^ (row & 7)];
            }
#pragma unroll
            for (int ni = 0; ni < 4; ++ni) {
                const int col = n0 + wn * 64 + ni * 16 + l15;
                bf[ni] = *(const f16x8*)(Wt + (size_t)col * K + kc + ks * 32 + lg * 8);
            }
#pragma unroll
            for (int mi = 0; mi < 4; ++mi)
#pragma unroll
                for (int ni = 0; ni < 4; ++ni)
                    acc[mi][ni] = __builtin_amdgcn_mfma_f32_16x16x32_f16(
                        af[mi], bf[ni], acc[mi][ni], 0, 0, 0);
        }
    }
    const int head = (n0 + wn * 64) >> 6;
    float a4s[4], a4d[4];
#pragma unroll
    for (int ni = 0; ni < 4; ++ni) {
        a4s[ni] = a_s[head * 64 + ni * 16 + l15];
        a4d[ni] = a_d[head * 64 + ni * 16 + l15];
    }
#pragma unroll
    for (int mi = 0; mi < 4; ++mi)
#pragma unroll
        for (int j = 0; j < 4; ++j) {
            const int r = m0 + wm * 64 + mi * 16 + lg * 4 + j;
            if (r < M) {
                float s1 = 0.f, s2 = 0.f;
#pragma unroll
                for (int ni = 0; ni < 4; ++ni) {
                    const float v = acc[mi][ni][j];
                    s1 += v * a4s[ni];
                    s2 += v * a4d[ni];
                    hout[(size_t)r * Nn + n0 + wn * 64 + ni * 16 + l15] = (_Float16)v;
                }
#pragma unroll
                for (int o = 8; o; o >>= 1) {
                    s1 += __shfl_xor(s1, o);
                    s2 += __shfl_xor(s2, o);
                }
                if (l15 == 0) {
                    als[(size_t)r * H + head] = s1;
                    ald[(size_t)r * H + head] = s2;
                }
            }
        }
}

// ---------------- aggregation: shuffle-broadcast, no LDS/barriers, ----------
// 4 independent waves (= 4 nodes) per 256-thread block ------------------------

// H=4 (F=256): wave handles one node. lane = (edge t&15, head t>>4).
// Channels: lane t covers t*4..t*4+3 (head t>>4's 64-channel span).
__global__ __launch_bounds__(256) void gat_agg_h4(
    const __half* __restrict__ hhf, const float* __restrict__ als,
    const float* __restrict__ ald, const int* __restrict__ csrsrc,
    const int* __restrict__ offv, const float* __restrict__ bias,
    __half* __restrict__ outh, int N) {
    const int t = threadIdx.x & 63;
    const int n = blockIdx.x * 4 + (threadIdx.x >> 6);
    if (n >= N) return;
    const int eidx = t & 15, head = t >> 4, lbase = t & 48;
    const int start = offv[n];
    const int deg = offv[n + 1] - start;
    const float adh = ald[n * 4 + head];
    const float wself = __expf(LRELU(als[n * 4 + head] + adh));
    float acc[4];
    {
        float2 raw = *(const float2*)(hhf + (size_t)n * 256 + t * 4);
        __half2 h0 = *(__half2*)&raw.x;
        __half2 h1 = *(__half2*)&raw.y;
        float2 a0 = __half22float2(h0), a1 = __half22float2(h1);
        acc[0] = a0.x * wself; acc[1] = a0.y * wself;
        acc[2] = a1.x * wself; acc[3] = a1.y * wself;
    }
    float dsum = wself;

    for (int base = 0; base < deg; base += 16) {
        const int nb = min(16, deg - base);
        int s = 0;
        float w = 0.f;
        if (eidx < nb) {
            s = csrsrc[start + base + eidx];
            w = __expf(LRELU(als[s * 4 + head] + adh));
        }
#pragma unroll 4
        for (int i = 0; i < nb; ++i) {
            const int si = __shfl(s, lbase | i);
            const float wi = __shfl(w, lbase | i);
            float2 raw = *(const float2*)(hhf + (size_t)si * 256 + t * 4);
            __half2 h0 = *(__half2*)&raw.x;
            __half2 h1 = *(__half2*)&raw.y;
            float2 a0 = __half22float2(h0), a1 = __half22float2(h1);
            dsum += wi;
            acc[0] += a0.x * wi; acc[1] += a0.y * wi;
            acc[2] += a1.x * wi; acc[3] += a1.y * wi;
        }
    }
    const float inv = 1.f / (dsum + 1e-16f);
    const float4 bv = *(const float4*)(bias + t * 4);
    float4 o4;
    o4.x = acc[0] * inv + bv.x;
    o4.y = acc[1] * inv + bv.y;
    o4.z = acc[2] * inv + bv.z;
    o4.w = acc[3] * inv + bv.w;
    // ELU
    o4.x = (o4.x > 0.f) ? o4.x : (__expf(o4.x) - 1.f);
    o4.y = (o4.y > 0.f) ? o4.y : (__expf(o4.y) - 1.f);
    o4.z = (o4.z > 0.f) ? o4.z : (__expf(o4.z) - 1.f);
    o4.w = (o4.w > 0.f) ? o4.w : (__expf(o4.w) - 1.f);
    __half2 p0 = __floats2half2_rn(o4.x, o4.y);
    __half2 p1 = __floats2half2_rn(o4.z, o4.w);
    float2 st;
    *(__half2*)&st.x = p0;
    *(__half2*)&st.y = p1;
    *(float2*)(outh + (size_t)n * 256 + t * 4) = st;
}

// H=1 (F=64) + ReLU + classifier + log_softmax, fully shuffle-based.
__global__ __launch_bounds__(256) void gat_agg_h1_cls(
    const __half* __restrict__ hhf, const float* __restrict__ als,
    const float* __restrict__ ald, const int* __restrict__ csrsrc,
    const int* __restrict__ offv, const float* __restrict__ bias,
    const float* __restrict__ cW1, const float* __restrict__ cb1,
    const float* __restrict__ cW2, const float* __restrict__ cb2,
    float* __restrict__ outp, int N) {
    const int t = threadIdx.x & 63;
    const int n = blockIdx.x * 4 + (threadIdx.x >> 6);
    if (n >= N) return;
    const int start = offv[n];
    const int deg = offv[n + 1] - start;
    const float ad = ald[n];
    const float wself = __expf(LRELU(als[n] + ad));
    float acc = __half2float(hhf[(size_t)n * 64 + t]) * wself;
    float dsum = wself;

    for (int base = 0; base < deg; base += 64) {
        const int nb = deg - base;
        int s = 0;
        float w = 0.f;
        if (t < nb) {
            s = csrsrc[start + base + t];
            w = __expf(LRELU(als[s] + ad));
        }
        const int nbc = min(nb, 64);
#pragma unroll 4
        for (int i = 0; i < nbc; ++i) {
            const int si = __shfl(s, i);
            const float wi = __shfl(w, i);
            dsum += wi;
            acc += __half2float(hhf[(size_t)si * 64 + t]) * wi;
        }
    }
    const float val = fmaxf(acc / (dsum + 1e-16f) + bias[t], 0.f);
    // ---- classifier: hid = relu(x@cW1+cb1); every lane computes hid[t&31] ----
    float s1 = cb1[t & 31];
#pragma unroll
    for (int c = 0; c < 64; ++c) {
        const float xv = __shfl(val, c);           // lane-uniform
        s1 += xv * cW1[c * 32 + (t & 31)];
    }
    const float hidv = fmaxf(s1, 0.f);             // lanes 32-63 duplicate 0-31
    float s2 = cb2[t & 1];
#pragma unroll
    for (int j = 0; j < 32; ++j) {
        const float hj = __shfl(hidv, j);          // lane-uniform
        s2 += hj * cW2[j * 2 + (t & 1)];
    }
    // s2 == logit[t&1] on every lane
    const float a = __shfl(s2, 0);
    const float b = __shfl(s2, 1);
    const float mm = fmaxf(a, b);
    const float lse = mm + logf(__expf(a - mm) + __expf(b - mm));
    if (t < 2) outp[(size_t)n * 2 + t] = s2 - lse;
}

extern "C" void kernel_launch(void* const* d_in, const int* in_sizes, int n_in,
                              void* d_out, int out_size, void* d_ws, size_t ws_size,
                              hipStream_t stream) {
    const float* x   = (const float*)d_in[0];
    const int*   ei  = (const int*)d_in[1];
    const float* W1  = (const float*)d_in[2];
    const float* a1s = (const float*)d_in[3];
    const float* a1d = (const float*)d_in[4];
    const float* b1  = (const float*)d_in[5];
    const float* W2  = (const float*)d_in[6];
    const float* a2s = (const float*)d_in[7];
    const float* a2d = (const float*)d_in[8];
    const float* b2  = (const float*)d_in[9];
    const float* W3  = (const float*)d_in[10];
    const float* a3s = (const float*)d_in[11];
    const float* a3d = (const float*)d_in[12];
    const float* b3  = (const float*)d_in[13];
    const float* cW1 = (const float*)d_in[14];
    const float* cb1 = (const float*)d_in[15];
    const float* cW2 = (const float*)d_in[16];
    const float* cb2 = (const float*)d_in[17];

    const int N = in_sizes[0] / 128;   // 50000
    const int E = in_sizes[1] / 2;     // 500000
    const int* srcv = ei;
    const int* dstv = ei + E;

    // workspace layout, all segments 16B-aligned
    char* p = (char*)d_ws;
    _Float16* slotA = (_Float16*)p; p += (size_t)N * 256 * 2;   // h1h / h2h / h3h
    _Float16* slotB = (_Float16*)p; p += (size_t)N * 256 * 2;   // a1h / a2h
    _Float16* slotC = (_Float16*)p; p += (size_t)N * 128 * 2;   // xh
    float* als = (float*)p; p += (size_t)N * 4 * 4;
    float* ald = (float*)p; p += (size_t)N * 4 * 4;
    int* cnt = (int*)p; p += (size_t)N * 4;
    int* offv = (int*)p; p += (size_t)(N + 4) * 4;
    int* csr = (int*)p; p += (size_t)E * 4;
    _Float16* Wt1 = (_Float16*)p; p += (size_t)128 * 256 * 2;
    _Float16* Wt2 = (_Float16*)p; p += (size_t)256 * 256 * 2;
    _Float16* Wt3 = (_Float16*)p; p += (size_t)256 * 64 * 2;
    int* bsum = (int*)p;

    // weight/input conversions (independent of CSR)
    prep_w16<<<(128 * 256 + 255) / 256, 256, 0, stream>>>(W1, Wt1, 128, 256);
    prep_w16<<<(256 * 256 + 255) / 256, 256, 0, stream>>>(W2, Wt2, 256, 256);
    prep_w16<<<(256 * 64 + 255) / 256, 256, 0, stream>>>(W3, Wt3, 256, 64);
    cvt_f16<<<(N * 128 / 4 + 255) / 256, 256, 0, stream>>>(x, slotC, N * 128 / 4);

    // CSR by destination
    const int NB = (N + 1023) / 1024;   // 49
    hipMemsetAsync(cnt, 0, (size_t)N * sizeof(int), stream);
    hist_kernel<<<(E + 255) / 256, 256, 0, stream>>>(dstv, cnt, E);
    scan_blk<<<NB, 256, 0, stream>>>(cnt, offv, bsum, N);
    scan_top<<<1, 64, 0, stream>>>(bsum, offv, NB, N);
    scan_add<<<NB, 256, 0, stream>>>(offv, bsum, N);
    hipMemsetAsync(cnt, 0, (size_t)N * sizeof(int), stream);
    fill_kernel<<<(E + 255) / 256, 256, 0, stream>>>(dstv, srcv, offv, cnt, csr, E);

    const int MB128 = (N + 127) / 128;   // 391
    const int MB256 = (N + 255) / 256;   // 196
    const int AGG = (N + 3) / 4;         // 12500

    // ---- layer 1 (128 -> 256, H=4, ELU) ----
    gemm_f16_fused<2, 4, 128, 4><<<dim3(MB128, 1), 512, 0, stream>>>(
        slotC, Wt1, a1s, a1d, slotA, als, ald, N, 256);
    gat_agg_h4<<<AGG, 256, 0, stream>>>((const __half*)slotA, als, ald, csr, offv,
                                        b1, (__half*)slotB, N);

    // ---- layer 2 (256 -> 256, H=4, ELU) ----
    gemm_f16_fused<2, 4, 256, 4><<<dim3(MB128, 1), 512, 0, stream>>>(
        slotB, Wt2, a2s, a2d, slotA, als, ald, N, 256);
    gat_agg_h4<<<AGG, 256, 0, stream>>>((const __half*)slotA, als, ald, csr, offv,
                                        b2, (__half*)slotB, N);

    // ---- layer 3 (256 -> 64, H=1) + agg + classifier + log_softmax ----
    gemm_f16_fused<4, 1, 256, 1><<<dim3(MB256, 1), 256, 0, stream>>>(
        slotB, Wt3, a3s, a3d, slotA, als, ald, N, 64);
    gat_agg_h1_cls<<<AGG, 256, 0, stream>>>((const __half*)slotA, als, ald, csr,
                                            offv, b3, cW1, cb1, cW2, cb2,
                                            (float*)d_out, N);
}

// Round 8
// 288.896 us; speedup vs baseline: 1.1360x; 1.1360x over previous
//
#include <hip/hip_runtime.h>
#include <hip/hip_fp16.h>

#define LRELU(v) ((v) > 0.f ? (v) : 0.2f * (v))

typedef _Float16 f16x8 __attribute__((ext_vector_type(8)));
typedef float f32x4 __attribute__((ext_vector_type(4)));

__device__ __forceinline__ f16x8 f16x8_zero() {
    f16x8 v;
#pragma unroll
    for (int j = 0; j < 8; ++j) v[j] = (_Float16)0.f;
    return v;
}

// ---------------- CSR construction ----------------
__global__ __launch_bounds__(256) void hist_kernel(const int* __restrict__ dst,
                                                   int* __restrict__ cnt, int E) {
    int e = blockIdx.x * 256 + threadIdx.x;
    if (e < E) atomicAdd(&cnt[dst[e]], 1);
}

__global__ __launch_bounds__(256) void scan_blk(const int* __restrict__ cnt,
                                                int* __restrict__ offv,
                                                int* __restrict__ bsum, int N) {
    __shared__ int sh[256];
    const int t = threadIdx.x;
    const int base = blockIdx.x * 1024 + t * 4;
    int v0 = (base + 0 < N) ? cnt[base + 0] : 0;
    int v1 = (base + 1 < N) ? cnt[base + 1] : 0;
    int v2 = (base + 2 < N) ? cnt[base + 2] : 0;
    int v3 = (base + 3 < N) ? cnt[base + 3] : 0;
    const int T = v0 + v1 + v2 + v3;
    sh[t] = T;
    __syncthreads();
    for (int o = 1; o < 256; o <<= 1) {
        int x = (t >= o) ? sh[t - o] : 0;
        __syncthreads();
        sh[t] += x;
        __syncthreads();
    }
    const int excl = sh[t] - T;
    if (t == 255) bsum[blockIdx.x] = sh[255];
    if (base + 0 < N) offv[base + 0] = excl;
    if (base + 1 < N) offv[base + 1] = excl + v0;
    if (base + 2 < N) offv[base + 2] = excl + v0 + v1;
    if (base + 3 < N) offv[base + 3] = excl + v0 + v1 + v2;
}

__global__ __launch_bounds__(64) void scan_top(int* __restrict__ bsum,
                                               int* __restrict__ offv,
                                               int NB, int N) {
    const int t = threadIdx.x;
    const int v = (t < NB) ? bsum[t] : 0;
    int incl = v;
#pragma unroll
    for (int o = 1; o < 64; o <<= 1) {
        int x = __shfl_up(incl, o);
        if (t >= o) incl += x;
    }
    if (t < NB) bsum[t] = incl - v;
    if (t == NB - 1) offv[N] = incl;
}

__global__ __launch_bounds__(256) void scan_add(int* __restrict__ offv,
                                                const int* __restrict__ bsum, int N) {
    const int base = blockIdx.x * 1024 + threadIdx.x * 4;
    const int add = bsum[blockIdx.x];
#pragma unroll
    for (int i = 0; i < 4; ++i)
        if (base + i < N) offv[base + i] += add;
}

__global__ __launch_bounds__(256) void fill_kernel(const int* __restrict__ dst,
                                                   const int* __restrict__ srcv,
                                                   const int* __restrict__ offv,
                                                   int* __restrict__ cur,
                                                   int* __restrict__ csrsrc, int E) {
    int e = blockIdx.x * 256 + threadIdx.x;
    if (e < E) {
        int d = dst[e];
        int p = atomicAdd(&cur[d], 1);
        csrsrc[offv[d] + p] = srcv[e];
    }
}

// ---------------- weight prep: transpose f32 [K][Nn] -> f16 [Nn][K] ----------------
__global__ __launch_bounds__(256) void prep_w16(const float* __restrict__ W,
                                                _Float16* __restrict__ wt,
                                                int K, int Nn) {
    int idx = blockIdx.x * 256 + threadIdx.x;
    if (idx < K * Nn) {
        int k = idx / Nn, nn2 = idx - k * Nn;
        wt[(size_t)nn2 * K + k] = (_Float16)W[idx];
    }
}

// ---------------- f32 -> f16 convert (x input) ----------------
__global__ __launch_bounds__(256) void cvt_f16(const float* __restrict__ in,
                                               _Float16* __restrict__ out, int n4) {
    int i = blockIdx.x * 256 + threadIdx.x;
    if (i < n4) {
        float4 v = *(const float4*)(in + (size_t)i * 4);
        _Float16 o[4] = {(_Float16)v.x, (_Float16)v.y, (_Float16)v.z, (_Float16)v.w};
        *(float2*)(out + (size_t)i * 4) = *(float2*)o;
    }
}

// ---------------- f16 MFMA GEMM, LDS-staged A, fused alpha + f16 h out ----------
template <int WM, int WN, int K, int H>
__global__ __launch_bounds__(WM * WN * 64) void gemm_f16_fused(
    const _Float16* __restrict__ A, const _Float16* __restrict__ Wt,
    const float* __restrict__ a_s, const float* __restrict__ a_d,
    _Float16* __restrict__ hout, float* __restrict__ als,
    float* __restrict__ ald, int M, int Nn) {
    constexpr int BM = WM * 64;
    constexpr int T = WM * WN * 64;
    constexpr int CHUNKS = BM * 16;
    __shared__ f16x8 Atile[BM * 16];
    const int t = threadIdx.x;
    const int lane = t & 63;
    const int wv = t >> 6;
    const int wm = wv / WN, wn = wv % WN;
    const int m0 = blockIdx.x * BM;
    const int n0 = blockIdx.y * (WN * 64);
    const int l15 = lane & 15, lg = lane >> 4;

    f32x4 acc[4][4];
    const f32x4 zz = {0.f, 0.f, 0.f, 0.f};
#pragma unroll
    for (int mi = 0; mi < 4; ++mi)
#pragma unroll
        for (int ni = 0; ni < 4; ++ni) acc[mi][ni] = zz;

    for (int kc = 0; kc < K; kc += 128) {
        __syncthreads();
#pragma unroll
        for (int i = 0; i < CHUNKS / T; ++i) {
            const int c = i * T + t;
            const int row = c >> 4, cc = c & 15;
            const int gr = m0 + row;
            f16x8 v = (gr < M) ? *(const f16x8*)(A + (size_t)gr * K + kc + cc * 8)
                               : f16x8_zero();
            Atile[(row * 16 + cc) ^ (row & 7)] = v;
        }
        __syncthreads();
#pragma unroll
        for (int ks = 0; ks < 4; ++ks) {
            f16x8 af[4], bf[4];
#pragma unroll
            for (int mi = 0; mi < 4; ++mi) {
                const int row = wm * 64 + mi * 16 + l15;
                af[mi] = Atile[(row * 16 + ks * 4 + lg) ^ (row & 7)];
            }
#pragma unroll
            for (int ni = 0; ni < 4; ++ni) {
                const int col = n0 + wn * 64 + ni * 16 + l15;
                bf[ni] = *(const f16x8*)(Wt + (size_t)col * K + kc + ks * 32 + lg * 8);
            }
#pragma unroll
            for (int mi = 0; mi < 4; ++mi)
#pragma unroll
                for (int ni = 0; ni < 4; ++ni)
                    acc[mi][ni] = __builtin_amdgcn_mfma_f32_16x16x32_f16(
                        af[mi], bf[ni], acc[mi][ni], 0, 0, 0);
        }
    }
    const int head = (n0 + wn * 64) >> 6;
    float a4s[4], a4d[4];
#pragma unroll
    for (int ni = 0; ni < 4; ++ni) {
        a4s[ni] = a_s[head * 64 + ni * 16 + l15];
        a4d[ni] = a_d[head * 64 + ni * 16 + l15];
    }
#pragma unroll
    for (int mi = 0; mi < 4; ++mi)
#pragma unroll
        for (int j = 0; j < 4; ++j) {
            const int r = m0 + wm * 64 + mi * 16 + lg * 4 + j;
            if (r < M) {
                float s1 = 0.f, s2 = 0.f;
#pragma unroll
                for (int ni = 0; ni < 4; ++ni) {
                    const float v = acc[mi][ni][j];
                    s1 += v * a4s[ni];
                    s2 += v * a4d[ni];
                    hout[(size_t)r * Nn + n0 + wn * 64 + ni * 16 + l15] = (_Float16)v;
                }
#pragma unroll
                for (int o = 8; o; o >>= 1) {
                    s1 += __shfl_xor(s1, o);
                    s2 += __shfl_xor(s2, o);
                }
                if (l15 == 0) {
                    als[(size_t)r * H + head] = s1;
                    ald[(size_t)r * H + head] = s2;
                }
            }
        }
}

// ---------------- aggregation: per-wave LDS slices (broadcast reads), ----------
// no cross-wave barriers, 4 nodes per 256-thread block, split accumulators -----

// H=4 (F=256): one wave per node; lane t covers channels t*4..t*4+3, head=t>>4.
__global__ __launch_bounds__(256) void gat_agg_h4(
    const __half* __restrict__ hhf, const float4* __restrict__ als4,
    const float4* __restrict__ ald4, const int* __restrict__ csrsrc,
    const int* __restrict__ offv, const float* __restrict__ bias,
    __half* __restrict__ outh, int N) {
    __shared__ int sidAll[4][64];
    __shared__ float wAll[4][64 * 4];
    const int wv = threadIdx.x >> 6;
    const int t = threadIdx.x & 63;
    const int n = blockIdx.x * 4 + wv;
    if (n >= N) return;
    const int hh = t >> 4;
    int* sid = sidAll[wv];
    float* wsh = wAll[wv];
    const int start = offv[n];
    const int deg = offv[n + 1] - start;
    const float4 ad = ald4[n];
    const float4 asf = als4[n];
    float wself;
    {
        float4 w4;
        w4.x = __expf(LRELU(asf.x + ad.x));
        w4.y = __expf(LRELU(asf.y + ad.y));
        w4.z = __expf(LRELU(asf.z + ad.z));
        w4.w = __expf(LRELU(asf.w + ad.w));
        float r = w4.x;
        r = (hh == 1) ? w4.y : r;
        r = (hh == 2) ? w4.z : r;
        r = (hh == 3) ? w4.w : r;
        wself = r;
    }
    float accA[4], accB[4] = {0.f, 0.f, 0.f, 0.f};
    {
        float2 raw = *(const float2*)(hhf + (size_t)n * 256 + t * 4);
        __half2 h0 = *(__half2*)&raw.x;
        __half2 h1 = *(__half2*)&raw.y;
        float2 a0 = __half22float2(h0), a1 = __half22float2(h1);
        accA[0] = a0.x * wself; accA[1] = a0.y * wself;
        accA[2] = a1.x * wself; accA[3] = a1.y * wself;
    }
    float dsA = wself, dsB = 0.f;

    for (int base = 0; base < deg; base += 64) {
        const int nb = min(64, deg - base);
        int s = 0;
        float4 w4 = {0.f, 0.f, 0.f, 0.f};
        if (t < nb) {
            s = csrsrc[start + base + t];
            const float4 av = als4[s];
            w4.x = __expf(LRELU(av.x + ad.x));
            w4.y = __expf(LRELU(av.y + ad.y));
            w4.z = __expf(LRELU(av.z + ad.z));
            w4.w = __expf(LRELU(av.w + ad.w));
        }
        sid[t] = s;
        *(float4*)(wsh + t * 4) = w4;
        __threadfence_block();   // lgkm fence: same-wave LDS write->read ordering
        // split even/odd edges over two accumulator sets (2 gathers in flight)
        int i = 0;
        for (; i + 1 < nb; i += 2) {
            const int sA = sid[i];
            const float wA = wsh[i * 4 + hh];
            const int sB = sid[i + 1];
            const float wB = wsh[(i + 1) * 4 + hh];
            float2 rA = *(const float2*)(hhf + (size_t)sA * 256 + t * 4);
            float2 rB = *(const float2*)(hhf + (size_t)sB * 256 + t * 4);
            __half2 a0 = *(__half2*)&rA.x, a1 = *(__half2*)&rA.y;
            __half2 b0 = *(__half2*)&rB.x, b1 = *(__half2*)&rB.y;
            float2 fa0 = __half22float2(a0), fa1 = __half22float2(a1);
            float2 fb0 = __half22float2(b0), fb1 = __half22float2(b1);
            dsA += wA; dsB += wB;
            accA[0] += fa0.x * wA; accA[1] += fa0.y * wA;
            accA[2] += fa1.x * wA; accA[3] += fa1.y * wA;
            accB[0] += fb0.x * wB; accB[1] += fb0.y * wB;
            accB[2] += fb1.x * wB; accB[3] += fb1.y * wB;
        }
        if (i < nb) {
            const int sA = sid[i];
            const float wA = wsh[i * 4 + hh];
            float2 rA = *(const float2*)(hhf + (size_t)sA * 256 + t * 4);
            __half2 a0 = *(__half2*)&rA.x, a1 = *(__half2*)&rA.y;
            float2 fa0 = __half22float2(a0), fa1 = __half22float2(a1);
            dsA += wA;
            accA[0] += fa0.x * wA; accA[1] += fa0.y * wA;
            accA[2] += fa1.x * wA; accA[3] += fa1.y * wA;
        }
        __threadfence_block();   // reads done before next chunk's writes
    }
    const float inv = 1.f / (dsA + dsB + 1e-16f);
    const float4 bv = *(const float4*)(bias + t * 4);
    float4 o4;
    o4.x = (accA[0] + accB[0]) * inv + bv.x;
    o4.y = (accA[1] + accB[1]) * inv + bv.y;
    o4.z = (accA[2] + accB[2]) * inv + bv.z;
    o4.w = (accA[3] + accB[3]) * inv + bv.w;
    // ELU
    o4.x = (o4.x > 0.f) ? o4.x : (__expf(o4.x) - 1.f);
    o4.y = (o4.y > 0.f) ? o4.y : (__expf(o4.y) - 1.f);
    o4.z = (o4.z > 0.f) ? o4.z : (__expf(o4.z) - 1.f);
    o4.w = (o4.w > 0.f) ? o4.w : (__expf(o4.w) - 1.f);
    __half2 p0 = __floats2half2_rn(o4.x, o4.y);
    __half2 p1 = __floats2half2_rn(o4.z, o4.w);
    float2 st;
    *(__half2*)&st.x = p0;
    *(__half2*)&st.y = p1;
    *(float2*)(outh + (size_t)n * 256 + t * 4) = st;
}

// H=1 (F=64) + ReLU + classifier + log_softmax; wave-parallel classifier.
__global__ __launch_bounds__(256) void gat_agg_h1_cls(
    const __half* __restrict__ hhf, const float* __restrict__ als,
    const float* __restrict__ ald, const int* __restrict__ csrsrc,
    const int* __restrict__ offv, const float* __restrict__ bias,
    const float* __restrict__ cW1, const float* __restrict__ cb1,
    const float* __restrict__ cW2, const float* __restrict__ cb2,
    float* __restrict__ outp, int N) {
    __shared__ float w1s[2048];   // cW1 [64][32]
    __shared__ float w2s[64];     // cW2 [32][2]
    __shared__ int sidAll[4][64];
    __shared__ float wAll[4][64];
    __shared__ float xsAll[4][64];
    for (int i = threadIdx.x; i < 2048; i += 256) w1s[i] = cW1[i];
    if (threadIdx.x < 64) w2s[threadIdx.x] = cW2[threadIdx.x];
    __syncthreads();   // uniform, once
    const int wv = threadIdx.x >> 6;
    const int t = threadIdx.x & 63;
    const int n = blockIdx.x * 4 + wv;
    if (n >= N) return;
    int* sid = sidAll[wv];
    float* wsh = wAll[wv];
    float* xs = xsAll[wv];
    const int start = offv[n];
    const int deg = offv[n + 1] - start;
    const float ad = ald[n];
    const float wself = __expf(LRELU(als[n] + ad));
    float accA = __half2float(hhf[(size_t)n * 64 + t]) * wself;
    float accB = 0.f;
    float dsA = wself, dsB = 0.f;

    for (int base = 0; base < deg; base += 64) {
        const int nb = min(64, deg - base);
        int s = 0;
        float w = 0.f;
        if (t < nb) {
            s = csrsrc[start + base + t];
            w = __expf(LRELU(als[s] + ad));
        }
        sid[t] = s;
        wsh[t] = w;
        __threadfence_block();
        int i = 0;
        for (; i + 1 < nb; i += 2) {
            const int sA = sid[i];
            const float wA = wsh[i];
            const int sB = sid[i + 1];
            const float wB = wsh[i + 1];
            const float hA = __half2float(hhf[(size_t)sA * 64 + t]);
            const float hB = __half2float(hhf[(size_t)sB * 64 + t]);
            dsA += wA; dsB += wB;
            accA += hA * wA;
            accB += hB * wB;
        }
        if (i < nb) {
            const int sA = sid[i];
            const float wA = wsh[i];
            dsA += wA;
            accA += __half2float(hhf[(size_t)sA * 64 + t]) * wA;
        }
        __threadfence_block();
    }
    const float val = fmaxf((accA + accB) / (dsA + dsB + 1e-16f) + bias[t], 0.f);
    // ---- classifier, wave-parallel ----
    xs[t] = val;
    __threadfence_block();
    const int j = t & 31;
    const int half = t >> 5;   // lanes 0-31: c in [0,32); lanes 32-63: c in [32,64)
    float s1 = 0.f;
#pragma unroll
    for (int cc = 0; cc < 32; ++cc) {
        const int c = half * 32 + cc;
        s1 += xs[c] * w1s[c * 32 + j];
    }
    s1 += __shfl_xor(s1, 32);                 // combine halves -> full dot for col j
    const float hid = fmaxf(s1 + cb1[j], 0.f);   // hid[j] in lanes j and j+32
    // logits: lane t -> k = t&1, jj = t>>1 (0..31)
    const int k = t & 1, jj = t >> 1;
    const float hjj = __shfl(hid, jj);        // hid[jj]
    float s2 = hjj * w2s[jj * 2 + k];
#pragma unroll
    for (int o = 2; o < 64; o <<= 1) s2 += __shfl_xor(s2, o);   // parity-preserving
    s2 += cb2[k];                              // even lanes: logit0, odd: logit1
    const float a = __shfl(s2, 0);
    const float b = __shfl(s2, 1);
    const float mm = fmaxf(a, b);
    const float lse = mm + logf(__expf(a - mm) + __expf(b - mm));
    if (t < 2) outp[(size_t)n * 2 + t] = s2 - lse;
}

extern "C" void kernel_launch(void* const* d_in, const int* in_sizes, int n_in,
                              void* d_out, int out_size, void* d_ws, size_t ws_size,
                              hipStream_t stream) {
    const float* x   = (const float*)d_in[0];
    const int*   ei  = (const int*)d_in[1];
    const float* W1  = (const float*)d_in[2];
    const float* a1s = (const float*)d_in[3];
    const float* a1d = (const float*)d_in[4];
    const float* b1  = (const float*)d_in[5];
    const float* W2  = (const float*)d_in[6];
    const float* a2s = (const float*)d_in[7];
    const float* a2d = (const float*)d_in[8];
    const float* b2  = (const float*)d_in[9];
    const float* W3  = (const float*)d_in[10];
    const float* a3s = (const float*)d_in[11];
    const float* a3d = (const float*)d_in[12];
    const float* b3  = (const float*)d_in[13];
    const float* cW1 = (const float*)d_in[14];
    const float* cb1 = (const float*)d_in[15];
    const float* cW2 = (const float*)d_in[16];
    const float* cb2 = (const float*)d_in[17];

    const int N = in_sizes[0] / 128;   // 50000
    const int E = in_sizes[1] / 2;     // 500000
    const int* srcv = ei;
    const int* dstv = ei + E;

    // workspace layout, all segments 16B-aligned
    char* p = (char*)d_ws;
    _Float16* slotA = (_Float16*)p; p += (size_t)N * 256 * 2;   // h1h / h2h / h3h
    _Float16* slotB = (_Float16*)p; p += (size_t)N * 256 * 2;   // a1h / a2h
    _Float16* slotC = (_Float16*)p; p += (size_t)N * 128 * 2;   // xh
    float* als = (float*)p; p += (size_t)N * 4 * 4;
    float* ald = (float*)p; p += (size_t)N * 4 * 4;
    int* cnt = (int*)p; p += (size_t)N * 4;
    int* offv = (int*)p; p += (size_t)(N + 4) * 4;
    int* csr = (int*)p; p += (size_t)E * 4;
    _Float16* Wt1 = (_Float16*)p; p += (size_t)128 * 256 * 2;
    _Float16* Wt2 = (_Float16*)p; p += (size_t)256 * 256 * 2;
    _Float16* Wt3 = (_Float16*)p; p += (size_t)256 * 64 * 2;
    int* bsum = (int*)p;

    // weight/input conversions (independent of CSR)
    prep_w16<<<(128 * 256 + 255) / 256, 256, 0, stream>>>(W1, Wt1, 128, 256);
    prep_w16<<<(256 * 256 + 255) / 256, 256, 0, stream>>>(W2, Wt2, 256, 256);
    prep_w16<<<(256 * 64 + 255) / 256, 256, 0, stream>>>(W3, Wt3, 256, 64);
    cvt_f16<<<(N * 128 / 4 + 255) / 256, 256, 0, stream>>>(x, slotC, N * 128 / 4);

    // CSR by destination
    const int NB = (N + 1023) / 1024;   // 49
    hipMemsetAsync(cnt, 0, (size_t)N * sizeof(int), stream);
    hist_kernel<<<(E + 255) / 256, 256, 0, stream>>>(dstv, cnt, E);
    scan_blk<<<NB, 256, 0, stream>>>(cnt, offv, bsum, N);
    scan_top<<<1, 64, 0, stream>>>(bsum, offv, NB, N);
    scan_add<<<NB, 256, 0, stream>>>(offv, bsum, N);
    hipMemsetAsync(cnt, 0, (size_t)N * sizeof(int), stream);
    fill_kernel<<<(E + 255) / 256, 256, 0, stream>>>(dstv, srcv, offv, cnt, csr, E);

    const int MB128 = (N + 127) / 128;   // 391
    const int MB256 = (N + 255) / 256;   // 196
    const int AGG = (N + 3) / 4;         // 12500

    // ---- layer 1 (128 -> 256, H=4, ELU) ----
    gemm_f16_fused<2, 4, 128, 4><<<dim3(MB128, 1), 512, 0, stream>>>(
        slotC, Wt1, a1s, a1d, slotA, als, ald, N, 256);
    gat_agg_h4<<<AGG, 256, 0, stream>>>((const __half*)slotA, (const float4*)als,
                                        (const float4*)ald, csr, offv, b1,
                                        (__half*)slotB, N);

    // ---- layer 2 (256 -> 256, H=4, ELU) ----
    gemm_f16_fused<2, 4, 256, 4><<<dim3(MB128, 1), 512, 0, stream>>>(
        slotB, Wt2, a2s, a2d, slotA, als, ald, N, 256);
    gat_agg_h4<<<AGG, 256, 0, stream>>>((const __half*)slotA, (const float4*)als,
                                        (const float4*)ald, csr, offv, b2,
                                        (__half*)slotB, N);

    // ---- layer 3 (256 -> 64, H=1) + agg + classifier + log_softmax ----
    gemm_f16_fused<4, 1, 256, 1><<<dim3(MB256, 1), 256, 0, stream>>>(
        slotB, Wt3, a3s, a3d, slotA, als, ald, N, 64);
    gat_agg_h1_cls<<<AGG, 256, 0, stream>>>((const __half*)slotA, als, ald, csr,
                                            offv, b3, cW1, cb1, cW2, cb2,
                                            (float*)d_out, N);
}